// Round 1
// baseline (760.720 us; speedup 1.0000x reference)
//
#include <hip/hip_runtime.h>
#include <math.h>

#define B_    32
#define R_    4
#define IN_   1024
#define OUT_  1024
#define S_    16                 // i-splits per (b,r)
#define CHUNK (IN_ / S_)         // 64 i-iterations per block
#define NPRE  ((size_t)IN_ * OUT_ + OUT_)

#define C_HALF_LOG_2PI 0.9189385332046727f
#define INV_SQRT_2PI   0.3989422804014327f
#define INV_SQRT_2PI_S 3.9894228040143270f   // 1/(sqrt(2pi)*0.1)
#define LOG_MIN       -23.025850929940457f   // log(1e-10)
#define LOG_MAX        2.3025850929940460f   // log(10)

__device__ __forceinline__ float softplus_f(float x) {
    // stable: max(x,0) + log1p(exp(-|x|))
    return fmaxf(x, 0.0f) + log1pf(__expf(-fabsf(x)));
}

__global__ void init_kernel(float* __restrict__ out) {
    int idx = blockIdx.x * 256 + threadIdx.x;
    if (idx < B_ * OUT_ + 2) out[idx] = 0.0f;
}

__global__ void precomp_kernel(const float* __restrict__ ro,
                               const float* __restrict__ ro_bias,
                               float* __restrict__ sig,
                               float* __restrict__ lpb) {
    size_t idx = (size_t)blockIdx.x * 256 + threadIdx.x;
    if (idx >= NPRE) return;
    float rv = (idx < (size_t)IN_ * OUT_) ? ro[idx] : ro_bias[idx - (size_t)IN_ * OUT_];
    float sg = softplus_f(rv);
    sig[idx] = sg;
    lpb[idx] = -C_HALF_LOG_2PI - __logf(sg);
}

// per-component fused update: einsum acc, log-mixture sum, log-gaussian sum
#define PROC(E, M, SG, LB, ACC)                                              \
    {                                                                        \
        float w  = fmaf((E), (SG), (M));                                     \
        (ACC)    = fmaf(xv, w, (ACC));                                       \
        float t  = -0.5f * w * w;                                            \
        float g1 = fmaxf(__expf(t)          * INV_SQRT_2PI,   1e-10f);       \
        float g2 = fmaxf(__expf(100.0f * t) * INV_SQRT_2PI_S, 1e-10f);       \
        smix += __logf(0.5f * (g1 + g2));                                    \
        float lw = fmaf((E) * (E), -0.5f, (LB));                             \
        slpw += fminf(fmaxf(lw, LOG_MIN), LOG_MAX);                          \
    }

template <bool USE_WS>
__global__ __launch_bounds__(256)
void main_kernel(const float* __restrict__ x,
                 const float* __restrict__ mu,
                 const float* __restrict__ ro,
                 const float* __restrict__ mu_bias,
                 const float* __restrict__ ro_bias,
                 const float* __restrict__ eps,
                 const float* __restrict__ eps_bias,
                 const float* __restrict__ sig_ws,
                 const float* __restrict__ lpb_ws,
                 float* __restrict__ out) {
    const int tid = threadIdx.x;
    const int bid = blockIdx.x;
    const int s   = bid & (S_ - 1);
    const int r   = (bid >> 4) & (R_ - 1);
    const int b   = bid >> 6;
    const int i0  = s * CHUNK;

    __shared__ float xs[CHUNK];
    if (tid < CHUNK) xs[tid] = x[b * IN_ + i0 + tid];
    __syncthreads();

    const size_t row0 = ((size_t)(b * R_ + r) * IN_ + i0) * OUT_;
    const float4* eps4 = (const float4*)(eps + row0) + tid;
    const float4* mu4  = (const float4*)(mu + (size_t)i0 * OUT_) + tid;
    const float4* ro4  = (const float4*)(ro + (size_t)i0 * OUT_) + tid;
    const float4* sig4 = USE_WS ? (const float4*)(sig_ws + (size_t)i0 * OUT_) + tid : nullptr;
    const float4* lpb4 = USE_WS ? (const float4*)(lpb_ws + (size_t)i0 * OUT_) + tid : nullptr;

    float4 acc = {0.f, 0.f, 0.f, 0.f};
    float smix = 0.f, slpw = 0.f;

    for (int ii = 0; ii < CHUNK; ++ii) {
        const int stride = ii * (OUT_ / 4);
        float  xv = xs[ii];
        float4 e  = eps4[stride];
        float4 m  = mu4[stride];
        float4 sg, lb;
        if (USE_WS) {
            sg = sig4[stride];
            lb = lpb4[stride];
        } else {
            float4 rr = ro4[stride];
            sg.x = softplus_f(rr.x); lb.x = -C_HALF_LOG_2PI - __logf(sg.x);
            sg.y = softplus_f(rr.y); lb.y = -C_HALF_LOG_2PI - __logf(sg.y);
            sg.z = softplus_f(rr.z); lb.z = -C_HALF_LOG_2PI - __logf(sg.z);
            sg.w = softplus_f(rr.w); lb.w = -C_HALF_LOG_2PI - __logf(sg.w);
        }
        PROC(e.x, m.x, sg.x, lb.x, acc.x);
        PROC(e.y, m.y, sg.y, lb.y, acc.y);
        PROC(e.z, m.z, sg.z, lb.z, acc.z);
        PROC(e.w, m.w, sg.w, lb.w, acc.w);
    }

    // bias handled once per (b,r) by the s==0 block
    if (s == 0) {
        float4 eb = *((const float4*)(eps_bias + (size_t)(b * R_ + r) * OUT_) + tid);
        float4 mb = *((const float4*)mu_bias + tid);
        float4 sgb, lbb;
        if (USE_WS) {
            sgb = *((const float4*)(sig_ws + (size_t)IN_ * OUT_) + tid);
            lbb = *((const float4*)(lpb_ws + (size_t)IN_ * OUT_) + tid);
        } else {
            float4 rb = *((const float4*)ro_bias + tid);
            sgb.x = softplus_f(rb.x); lbb.x = -C_HALF_LOG_2PI - __logf(sgb.x);
            sgb.y = softplus_f(rb.y); lbb.y = -C_HALF_LOG_2PI - __logf(sgb.y);
            sgb.z = softplus_f(rb.z); lbb.z = -C_HALF_LOG_2PI - __logf(sgb.z);
            sgb.w = softplus_f(rb.w); lbb.w = -C_HALF_LOG_2PI - __logf(sgb.w);
        }
        float xv = 1.0f;   // acc += 1 * bias
        PROC(eb.x, mb.x, sgb.x, lbb.x, acc.x);
        PROC(eb.y, mb.y, sgb.y, lbb.y, acc.y);
        PROC(eb.z, mb.z, sgb.z, lbb.z, acc.z);
        PROC(eb.w, mb.w, sgb.w, lbb.w, acc.w);
    }

    // out[b, o] += acc / R  (mean over r, summed across s-splits via atomics)
    float* outp = out + (size_t)b * OUT_ + tid * 4;
    atomicAdd(outp + 0, acc.x * 0.25f);
    atomicAdd(outp + 1, acc.y * 0.25f);
    atomicAdd(outp + 2, acc.z * 0.25f);
    atomicAdd(outp + 3, acc.w * 0.25f);

    // block-reduce the two scalar sums, then one atomic pair per block
    for (int off = 32; off > 0; off >>= 1) {
        smix += __shfl_down(smix, off, 64);
        slpw += __shfl_down(slpw, off, 64);
    }
    __shared__ float red[8];
    const int wave = tid >> 6, lane = tid & 63;
    if (lane == 0) { red[wave] = smix; red[4 + wave] = slpw; }
    __syncthreads();
    if (tid == 0) {
        float sm = red[0] + red[1] + red[2] + red[3];
        float sl = red[4] + red[5] + red[6] + red[7];
        atomicAdd(out + B_ * OUT_ + 0, sm * (1.0f / 128.0f));
        atomicAdd(out + B_ * OUT_ + 1, sl * (1.0f / 128.0f));
    }
}

extern "C" void kernel_launch(void* const* d_in, const int* in_sizes, int n_in,
                              void* d_out, int out_size, void* d_ws, size_t ws_size,
                              hipStream_t stream) {
    const float* x       = (const float*)d_in[0];
    const float* mu      = (const float*)d_in[1];
    const float* ro      = (const float*)d_in[2];
    const float* mu_bias = (const float*)d_in[3];
    const float* ro_bias = (const float*)d_in[4];
    const float* eps     = (const float*)d_in[5];
    const float* eps_b   = (const float*)d_in[6];
    float* out = (float*)d_out;

    const bool use_ws = ws_size >= 2 * NPRE * sizeof(float);
    float* sig_ws = (float*)d_ws;
    float* lpb_ws = sig_ws + NPRE;

    init_kernel<<<(B_ * OUT_ + 2 + 255) / 256, 256, 0, stream>>>(out);

    if (use_ws) {
        precomp_kernel<<<(int)((NPRE + 255) / 256), 256, 0, stream>>>(ro, ro_bias, sig_ws, lpb_ws);
        main_kernel<true><<<B_ * R_ * S_, 256, 0, stream>>>(
            x, mu, ro, mu_bias, ro_bias, eps, eps_b, sig_ws, lpb_ws, out);
    } else {
        main_kernel<false><<<B_ * R_ * S_, 256, 0, stream>>>(
            x, mu, ro, mu_bias, ro_bias, eps, eps_b, nullptr, nullptr, out);
    }
}